// Round 1
// baseline (384.550 us; speedup 1.0000x reference)
//
#include <hip/hip_runtime.h>
#include <hip/hip_bf16.h>
#include <stdint.h>

#define M_ROWS 8192   // 4*2048
#define K_DIM  4096
#define N_DIM  4096
#define NKT    128    // K_DIM/32
#define QROWS  512    // K_DIM/32*4

using bf16 = __hip_bfloat16;
typedef __attribute__((ext_vector_type(4))) float f32x4;
typedef __attribute__((ext_vector_type(8))) short s16x8;

__device__ __forceinline__ void gll16(const void* g, void* l) {
  __builtin_amdgcn_global_load_lds(
      (const __attribute__((address_space(1))) void*)g,
      (__attribute__((address_space(3))) void*)l, 16, 0, 0);
}

// ---------------------------------------------------------------------------
// Dequant: qweight (512,4096) int32 + scales/scales2 (32,4096) ->
// bf16 W in packed panel layout Bp[nt][kt][col(128)][kk(32)],
// i.e. elem = (nt*128+kt)*4096 + col*32 + kk.  One thread = one int32 = 8 k's.
// ---------------------------------------------------------------------------
__global__ __launch_bounds__(256) void dequant_k(
    const int* __restrict__ qw, const float* __restrict__ s1,
    const float* __restrict__ s2, bf16* __restrict__ Bp)
{
  const int t = blockIdx.x * 256 + threadIdx.x;   // 0 .. 512*4096-1
  const int o = t & 4095;
  const int r = t >> 12;            // qweight row 0..511
  const int g = r >> 4;             // group = (r*8)/128
  const int kt = r >> 2;            // k-tile = (r*8)/32
  const int kk0 = (r & 3) * 8;

  const uint32_t wbits = (uint32_t)qw[(size_t)r * 4096 + o];
  const float a = s1[g * 4096 + o] * 0.5f;   // for codes >= 0 (q>=8)
  const float b = s2[g * 4096 + o] * 0.5f;   // for codes <  0 (q<8; q=7 -> 0)
  // 2*CODE packed as int8:  q=0..7: -12,-8,-6,-4,-3,-2,-1,0   q=8..15: 0,1,2,3,4,6,8,12
  const uint64_t lo = 0x00FFFEFDFCFAF8F4ull;
  const uint64_t hi = 0x0C08060403020100ull;

  union { bf16 h[8]; s16x8 v; } u;
  #pragma unroll
  for (int j = 0; j < 8; ++j) {
    const int q = (wbits >> (4 * j)) & 15;
    const uint64_t pk = (q & 8) ? hi : lo;
    const int c2 = (int)(int8_t)(uint8_t)(pk >> ((q & 7) * 8));
    const float s = (q & 8) ? a : b;
    u.h[j] = __float2bfloat16((float)c2 * s);
  }
  const int nt = o >> 7, col = o & 127;
  bf16* dst = Bp + (((size_t)(nt * 128 + kt) * 128 + col) * 32 + kk0);
  *(s16x8*)dst = u.v;
}

// x fp32 -> bf16, linear. 8 elems/thread.
__global__ __launch_bounds__(256) void xcast_k(const float* __restrict__ x,
                                               bf16* __restrict__ xb)
{
  const size_t t = (size_t)blockIdx.x * 256 + threadIdx.x;
  const float* s = x + t * 8;
  f32x4 v0 = *(const f32x4*)(s);
  f32x4 v1 = *(const f32x4*)(s + 4);
  union { bf16 h[8]; s16x8 v; } u;
  #pragma unroll
  for (int j = 0; j < 4; ++j) {
    u.h[j]     = __float2bfloat16(v0[j]);
    u.h[4 + j] = __float2bfloat16(v1[j]);
  }
  *(s16x8*)(xb + t * 8) = u.v;
}

// ---------------------------------------------------------------------------
// GEMM: out(8192,4096) = x(8192,4096) * W(4096,4096) + bias
// 128x128 tile, BK=32, 4 waves (2x2 of 64x64), mfma_f32_16x16x32_bf16.
// Double-buffered LDS, 2-phase schedule (stage next || compute cur, 1 barrier).
// ---------------------------------------------------------------------------
template <bool ABF>
__global__ __launch_bounds__(256) void gemm_k(
    const float* __restrict__ x, const bf16* __restrict__ xb,
    const bf16* __restrict__ Bp, const float* __restrict__ bias,
    float* __restrict__ out)
{
  __shared__ bf16 As[2][4096];   // [row(128)][k(32)]
  __shared__ bf16 Bs[2][4096];   // [col(128)][k(32)]

  const int id  = blockIdx.x;
  const int swz = (id & 7) * 256 + (id >> 3);   // bijective XCD swizzle (2048%8==0)
  const int tm  = swz >> 5;    // 0..63
  const int tn  = swz & 31;    // 0..31
  const int tid = threadIdx.x;
  const int lane = tid & 63;
  const int w   = tid >> 6;
  const int wr  = (w >> 1) * 64;
  const int wc  = (w & 1) * 64;
  const int lr  = lane & 15;
  const int lg  = lane >> 4;

  f32x4 acc[4][4];
  #pragma unroll
  for (int m = 0; m < 4; ++m)
    #pragma unroll
    for (int n = 0; n < 4; ++n) acc[m][n] = (f32x4){0.f, 0.f, 0.f, 0.f};

  const bf16* bsrc = Bp + ((size_t)tn << 19);  // tn*128*4096 elems
  const bf16* asrc_bf = nullptr;
  const float* asrc_f = nullptr;
  if constexpr (ABF) {
    asrc_bf = xb + ((size_t)(tm * 128 + (tid >> 2)) << 12) + (tid & 3) * 8;
  } else {
    asrc_f = x + ((size_t)(tm * 128 + (tid >> 1)) << 12) + (tid & 1) * 16;
  }

  float areg[16];

  auto stageB = [&](int kt, int buf) {
    const bf16* bs = bsrc + ((size_t)kt << 12);
    gll16(bs + tid * 8,        &Bs[buf][tid * 8]);
    gll16(bs + 2048 + tid * 8, &Bs[buf][2048 + tid * 8]);
  };
  auto stageA = [&](int kt, int buf) {   // ABF only
    const bf16* as = asrc_bf + ((size_t)kt << 5);
    gll16(as,                 &As[buf][tid * 8]);
    gll16(as + (64 << 12),    &As[buf][2048 + tid * 8]);
  };
  auto loadA = [&](int kt) {             // !ABF
    const float* s = asrc_f + ((size_t)kt << 5);
    #pragma unroll
    for (int i = 0; i < 4; ++i)
      *(f32x4*)(areg + i * 4) = *(const f32x4*)(s + i * 4);
  };
  auto writeA = [&](int buf) {           // !ABF
    union { bf16 h[16]; s16x8 v[2]; } u;
    #pragma unroll
    for (int i = 0; i < 16; ++i) u.h[i] = __float2bfloat16(areg[i]);
    bf16* d = &As[buf][(tid >> 1) * 32 + (tid & 1) * 16];
    *(s16x8*)d = u.v[0];
    *(s16x8*)(d + 8) = u.v[1];
  };
  auto compute = [&](int buf) {
    s16x8 af[4], bv[4];
    #pragma unroll
    for (int m = 0; m < 4; ++m)
      af[m] = *(const s16x8*)(&As[buf][(wr + m * 16 + lr) * 32 + lg * 8]);
    #pragma unroll
    for (int n = 0; n < 4; ++n)
      bv[n] = *(const s16x8*)(&Bs[buf][(wc + n * 16 + lr) * 32 + lg * 8]);
    #pragma unroll
    for (int m = 0; m < 4; ++m)
      #pragma unroll
      for (int n = 0; n < 4; ++n)
        acc[m][n] = __builtin_amdgcn_mfma_f32_16x16x32_bf16(af[m], bv[n],
                                                            acc[m][n], 0, 0, 0);
  };

  // prologue
  stageB(0, 0);
  if constexpr (ABF) {
    stageA(0, 0);
  } else {
    loadA(0);
    writeA(0);
  }
  __syncthreads();

  #pragma unroll 2
  for (int kt = 0; kt < NKT; ++kt) {
    const int buf = kt & 1;
    if (kt + 1 < NKT) {
      stageB(kt + 1, buf ^ 1);
      if constexpr (ABF) stageA(kt + 1, buf ^ 1);
      else loadA(kt + 1);
    }
    compute(buf);
    if constexpr (!ABF) {
      if (kt + 1 < NKT) writeA(buf ^ 1);
    }
    __syncthreads();   // drains vmcnt (gll) + lgkmcnt; next tile ready
  }

  // epilogue: D row=(lane>>4)*4+reg, col=lane&15
  const int orow0 = tm * 128 + wr + lg * 4;
  const int ocol0 = tn * 128 + wc + lr;
  float bvv[4];
  #pragma unroll
  for (int n = 0; n < 4; ++n) bvv[n] = bias[ocol0 + n * 16];
  #pragma unroll
  for (int m = 0; m < 4; ++m) {
    #pragma unroll
    for (int r = 0; r < 4; ++r) {
      const size_t row = (size_t)(orow0 + m * 16 + r);
      float* op = out + row * N_DIM + ocol0;
      #pragma unroll
      for (int n = 0; n < 4; ++n)
        op[n * 16] = acc[m][n][r] + bvv[n];
    }
  }
}

extern "C" void kernel_launch(void* const* d_in, const int* in_sizes, int n_in,
                              void* d_out, int out_size, void* d_ws, size_t ws_size,
                              hipStream_t stream) {
  const float* x    = (const float*)d_in[0];
  const int*   qw   = (const int*)d_in[1];
  const float* s1   = (const float*)d_in[2];
  const float* s2   = (const float*)d_in[3];
  const float* bias = (const float*)d_in[4];
  float* out = (float*)d_out;

  const size_t BP_BYTES = (size_t)K_DIM * N_DIM * 2;    // 32 MiB
  const size_t XB_BYTES = (size_t)M_ROWS * K_DIM * 2;   // 64 MiB
  bf16* Bp = (bf16*)d_ws;

  dequant_k<<<dim3(QROWS * N_DIM / 256), dim3(256), 0, stream>>>(qw, s1, s2, Bp);

  if (ws_size >= BP_BYTES + XB_BYTES) {
    bf16* xb = (bf16*)((char*)d_ws + BP_BYTES);
    xcast_k<<<dim3((size_t)M_ROWS * K_DIM / 8 / 256), dim3(256), 0, stream>>>(x, xb);
    gemm_k<true><<<dim3(2048), dim3(256), 0, stream>>>(x, xb, Bp, bias, out);
  } else {
    gemm_k<false><<<dim3(2048), dim3(256), 0, stream>>>(x, nullptr, Bp, bias, out);
  }
}

// Round 2
// 274.215 us; speedup vs baseline: 1.4024x; 1.4024x over previous
//
#include <hip/hip_runtime.h>
#include <hip/hip_bf16.h>
#include <stdint.h>

#define M_ROWS 8192
#define K_DIM  4096
#define N_DIM  4096
#define NTK    64     // K-tiles of 64

using bf16 = __hip_bfloat16;
typedef __attribute__((ext_vector_type(4))) float f32x4;
typedef __attribute__((ext_vector_type(8))) short s16x8;

__device__ __forceinline__ void gll16(const bf16* g, bf16* l) {
  __builtin_amdgcn_global_load_lds(
      (const __attribute__((address_space(1))) void*)g,
      (__attribute__((address_space(3))) void*)l, 16, 0, 0);
}

// ===========================================================================
// PATH A (8-phase 256^2): panel layouts, swizzle baked into global layout.
// A panels: chunk[(tm*64+kt)*2+kh] of 8192 bf16 = [row 256][slot 4][8],
//   data(row,slot_store) = x[tm*256+row][kt*64+kh*32+(slot_store^((row>>1)&3))*8..]
// B panels: chunk[(tn*64+kt)*2+kh] = [col 256][slot 4][8],
//   data(col,slot_store) = W[kt*64+kh*32+(slot_store^((col>>1)&3))*8+j][tn*256+col]
// ===========================================================================

// dequant -> swizzled B panels. thread = 4 consecutive qw rows x 1 col.
__global__ __launch_bounds__(256) void dequant8_k(
    const int* __restrict__ qw, const float* __restrict__ s1,
    const float* __restrict__ s2, bf16* __restrict__ Bp)
{
  const int t = blockIdx.x * 256 + threadIdx.x;   // 0..524287
  const int o = t & 4095;
  const int q = t >> 12;          // 0..127
  const int r0 = q << 2;
  const int g = r0 >> 4;
  const int nt = o >> 8, col = o & 255;
  const int kt = q >> 1, kh = q & 1;
  const int sw = (col >> 1) & 3;
  const float a = s1[g * 4096 + o] * 0.5f;   // codes >= 0 (q>=8)
  const float b = s2[g * 4096 + o] * 0.5f;   // codes <  0
  const uint64_t lo = 0x00FFFEFDFCFAF8F4ull;  // 2*CODE, q=0..7
  const uint64_t hi = 0x0C08060403020100ull;  // 2*CODE, q=8..15
  bf16* dst = Bp + (((size_t)((nt * 64 + kt) * 2 + kh)) << 13) + col * 32;
  #pragma unroll
  for (int j = 0; j < 4; ++j) {
    const uint32_t wbits = (uint32_t)qw[(size_t)(r0 + j) * 4096 + o];
    union { bf16 h[8]; s16x8 v; } u;
    #pragma unroll
    for (int i = 0; i < 8; ++i) {
      const int qc = (wbits >> (4 * i)) & 15;
      const uint64_t pk = (qc & 8) ? hi : lo;
      const int c2 = (int)(int8_t)(uint8_t)(pk >> ((qc & 7) * 8));
      const float sc = (qc & 8) ? a : b;
      u.h[i] = __float2bfloat16((float)c2 * sc);
    }
    *(s16x8*)(dst + ((j ^ sw) << 3)) = u.v;
  }
}

// x fp32 -> swizzled bf16 A panels.
__global__ __launch_bounds__(256) void xcast_k(const float* __restrict__ x,
                                               bf16* __restrict__ Ap)
{
  const int t = blockIdx.x * 256 + threadIdx.x;   // 0..4194303
  const int s_lin = t & 3;
  const int kh = (t >> 2) & 1;
  const int kt = (t >> 3) & 63;
  const int m  = t >> 9;
  const int tm = m >> 8, row = m & 255;
  const float* s = x + (size_t)m * 4096 + (kt * 64 + kh * 32 + s_lin * 8);
  f32x4 v0 = *(const f32x4*)s;
  f32x4 v1 = *(const f32x4*)(s + 4);
  union { bf16 h[8]; s16x8 v; } u;
  #pragma unroll
  for (int j = 0; j < 4; ++j) {
    u.h[j]     = __float2bfloat16(v0[j]);
    u.h[4 + j] = __float2bfloat16(v1[j]);
  }
  const int ss = s_lin ^ ((row >> 1) & 3);
  bf16* dst = Ap + (((size_t)((tm * 64 + kt) * 2 + kh)) << 13) + row * 32 + ss * 8;
  *(s16x8*)dst = u.v;
}

// ---------------------------------------------------------------------------
// 8-phase 256x256 GEMM, BK=64, 8 waves (2Mx4N), 128 KiB LDS dbuf,
// counted vmcnt(4), setprio around MFMA clusters, two barriers/phase.
// ---------------------------------------------------------------------------
#define PH_SYNC()                                                     \
    __builtin_amdgcn_s_barrier();                                     \
    asm volatile("s_waitcnt lgkmcnt(0)" ::: "memory");                \
    __builtin_amdgcn_sched_barrier(0)

#define MFMA16(MH)                                                    \
    __builtin_amdgcn_s_setprio(1);                                    \
    _Pragma("unroll")                                                 \
    for (int m = 0; m < 4; ++m) {                                     \
      _Pragma("unroll")                                               \
      for (int n = 0; n < 4; ++n)                                     \
        acc[(MH)*4+m][n] = __builtin_amdgcn_mfma_f32_16x16x32_bf16(   \
            af[m], bb[n], acc[(MH)*4+m][n], 0, 0, 0);                 \
    }                                                                 \
    __builtin_amdgcn_s_setprio(0)

#define KTILE(BUF, NK2, PRE, VM)                                      \
  {                                                                   \
    const bf16* A0_ = &lds[BUF][0][0];                                \
    const bf16* A1_ = &lds[BUF][1][0];                                \
    const bf16* B0_ = &lds[BUF][2][0];                                \
    const bf16* B1_ = &lds[BUF][3][0];                                \
    /* p0: (mh0,kk0) */                                               \
    _Pragma("unroll")                                                 \
    for (int m = 0; m < 4; ++m) af[m] = *(const s16x8*)(A0_ + aoff + m * 512); \
    _Pragma("unroll")                                                 \
    for (int n = 0; n < 4; ++n) bb[n] = *(const s16x8*)(B0_ + boff + n * 512); \
    if (PRE) stage(Ab, (NK2), &lds[(BUF)^1][0][0]);                   \
    PH_SYNC();                                                        \
    MFMA16(0);                                                        \
    __builtin_amdgcn_s_barrier();                                     \
    /* p1: (mh1,kk0) */                                               \
    _Pragma("unroll")                                                 \
    for (int m = 0; m < 4; ++m) af[m] = *(const s16x8*)(A0_ + aoff + (m + 4) * 512); \
    if (PRE) stage(Bb, (NK2), &lds[(BUF)^1][2][0]);                   \
    PH_SYNC();                                                        \
    MFMA16(1);                                                        \
    asm volatile("s_waitcnt vmcnt(" #VM ")" ::: "memory");            \
    __builtin_amdgcn_s_barrier();                                     \
    /* p2: (mh0,kk1) */                                               \
    _Pragma("unroll")                                                 \
    for (int m = 0; m < 4; ++m) af[m] = *(const s16x8*)(A1_ + aoff + m * 512); \
    _Pragma("unroll")                                                 \
    for (int n = 0; n < 4; ++n) bb[n] = *(const s16x8*)(B1_ + boff + n * 512); \
    if (PRE) stage(Ab, (NK2) + 1, &lds[(BUF)^1][1][0]);               \
    PH_SYNC();                                                        \
    MFMA16(0);                                                        \
    __builtin_amdgcn_s_barrier();                                     \
    /* p3: (mh1,kk1) */                                               \
    _Pragma("unroll")                                                 \
    for (int m = 0; m < 4; ++m) af[m] = *(const s16x8*)(A1_ + aoff + (m + 4) * 512); \
    if (PRE) stage(Bb, (NK2) + 1, &lds[(BUF)^1][3][0]);               \
    PH_SYNC();                                                        \
    MFMA16(1);                                                        \
    asm volatile("s_waitcnt vmcnt(" #VM ")" ::: "memory");            \
    __builtin_amdgcn_s_barrier();                                     \
  }

__global__ __launch_bounds__(512, 2) void gemm8_k(
    const bf16* __restrict__ Ap, const bf16* __restrict__ Bp,
    const float* __restrict__ bias, float* __restrict__ out)
{
  __shared__ bf16 lds[2][4][8192];   // [buf][A-k0, A-k1, B-k0, B-k1]  128 KiB

  const int id  = blockIdx.x;
  const int swz = (id & 7) * 64 + (id >> 3);   // 512 % 8 == 0: bijective
  const int tm  = swz >> 4;      // 0..31
  const int tn  = swz & 15;      // 0..15
  const int tid = (int)threadIdx.x;
  const int lane = tid & 63;
  const int w   = tid >> 6;
  const int wr  = w >> 2;        // 0..1
  const int wc  = w & 3;         // 0..3
  const int lr  = lane & 15;
  const int lg  = lane >> 4;
  const int sl  = (lg ^ ((lr >> 1) & 3)) << 3;      // swizzled slot (elems)
  const int aoff = (wr * 128 + lr) * 32 + sl;
  const int boff = (wc * 64 + lr) * 32 + sl;

  const bf16* Ab = Ap + ((size_t)tm << 20);
  const bf16* Bb = Bp + ((size_t)tn << 20);

  f32x4 acc[8][4];
  #pragma unroll
  for (int m = 0; m < 8; ++m)
    #pragma unroll
    for (int n = 0; n < 4; ++n) acc[m][n] = (f32x4){0.f, 0.f, 0.f, 0.f};

  auto stage = [&](const bf16* base, int c, bf16* dst) {
    const bf16* s = base + ((size_t)c << 13) + tid * 8;
    gll16(s, dst + tid * 8);
    gll16(s + 4096, dst + tid * 8 + 4096);
  };

  s16x8 af[4], bb[4];

  // prologue: stage T0 halves in need-order A0,B0,A1,B1; keep A1,B1 in flight
  stage(Ab, 0, &lds[0][0][0]);
  stage(Bb, 0, &lds[0][2][0]);
  stage(Ab, 1, &lds[0][1][0]);
  stage(Bb, 1, &lds[0][3][0]);
  asm volatile("s_waitcnt vmcnt(4)" ::: "memory");
  __builtin_amdgcn_s_barrier();

  #pragma unroll 1
  for (int kt2 = 0; kt2 < 31; ++kt2) {
    const int nka = (2 * kt2 + 1) * 2;
    const int nkb = (2 * kt2 + 2) * 2;
    KTILE(0, nka, 1, 4);
    KTILE(1, nkb, 1, 4);
  }
  KTILE(0, 126, 1, 4);   // kt=62, stages T63
  KTILE(1, 0, 0, 0);     // kt=63, drain

  // epilogue: D row=(lane>>4)*4+reg, col=lane&15
  const int orow0 = tm * 256 + wr * 128 + lg * 4;
  const int ocol0 = tn * 256 + wc * 64 + lr;
  float bv[4];
  #pragma unroll
  for (int n = 0; n < 4; ++n) bv[n] = bias[ocol0 + n * 16];
  #pragma unroll
  for (int m = 0; m < 8; ++m) {
    #pragma unroll
    for (int r = 0; r < 4; ++r) {
      float* op = out + (size_t)(orow0 + m * 16 + r) * N_DIM + ocol0;
      #pragma unroll
      for (int n = 0; n < 4; ++n) op[n * 16] = acc[m][n][r] + bv[n];
    }
  }
}

// ===========================================================================
// PATH B fallback (round-1 verified): 128^2 tile, fp32 A reg-staged.
// ===========================================================================
__global__ __launch_bounds__(256) void dequant_f(
    const int* __restrict__ qw, const float* __restrict__ s1,
    const float* __restrict__ s2, bf16* __restrict__ Bp)
{
  const int t = blockIdx.x * 256 + threadIdx.x;
  const int o = t & 4095;
  const int r = t >> 12;
  const int g = r >> 4;
  const int kt = r >> 2;
  const int kk0 = (r & 3) * 8;
  const uint32_t wbits = (uint32_t)qw[(size_t)r * 4096 + o];
  const float a = s1[g * 4096 + o] * 0.5f;
  const float b = s2[g * 4096 + o] * 0.5f;
  const uint64_t lo = 0x00FFFEFDFCFAF8F4ull;
  const uint64_t hi = 0x0C08060403020100ull;
  union { bf16 h[8]; s16x8 v; } u;
  #pragma unroll
  for (int j = 0; j < 8; ++j) {
    const int q = (wbits >> (4 * j)) & 15;
    const uint64_t pk = (q & 8) ? hi : lo;
    const int c2 = (int)(int8_t)(uint8_t)(pk >> ((q & 7) * 8));
    const float s = (q & 8) ? a : b;
    u.h[j] = __float2bfloat16((float)c2 * s);
  }
  const int nt = o >> 7, col = o & 127;
  bf16* dst = Bp + (((size_t)(nt * 128 + kt) * 128 + col) * 32 + kk0);
  *(s16x8*)dst = u.v;
}

__global__ __launch_bounds__(256) void gemmf_k(
    const float* __restrict__ x, const bf16* __restrict__ Bp,
    const float* __restrict__ bias, float* __restrict__ out)
{
  __shared__ bf16 As[2][4096];
  __shared__ bf16 Bs[2][4096];

  const int id  = blockIdx.x;
  const int swz = (id & 7) * 256 + (id >> 3);
  const int tm  = swz >> 5;
  const int tn  = swz & 31;
  const int tid = threadIdx.x;
  const int lane = tid & 63;
  const int w   = tid >> 6;
  const int wr  = (w >> 1) * 64;
  const int wc  = (w & 1) * 64;
  const int lr  = lane & 15;
  const int lg  = lane >> 4;

  f32x4 acc[4][4];
  #pragma unroll
  for (int m = 0; m < 4; ++m)
    #pragma unroll
    for (int n = 0; n < 4; ++n) acc[m][n] = (f32x4){0.f, 0.f, 0.f, 0.f};

  const bf16* bsrc = Bp + ((size_t)tn << 19);
  const float* asrc_f = x + ((size_t)(tm * 128 + (tid >> 1)) << 12) + (tid & 1) * 16;
  float areg[16];

  auto stageB = [&](int kt, int buf) {
    const bf16* bs = bsrc + ((size_t)kt << 12);
    gll16(bs + tid * 8,        &Bs[buf][tid * 8]);
    gll16(bs + 2048 + tid * 8, &Bs[buf][2048 + tid * 8]);
  };
  auto loadA = [&](int kt) {
    const float* s = asrc_f + ((size_t)kt << 5);
    #pragma unroll
    for (int i = 0; i < 4; ++i)
      *(f32x4*)(areg + i * 4) = *(const f32x4*)(s + i * 4);
  };
  auto writeA = [&](int buf) {
    union { bf16 h[16]; s16x8 v[2]; } u;
    #pragma unroll
    for (int i = 0; i < 16; ++i) u.h[i] = __float2bfloat16(areg[i]);
    bf16* d = &As[buf][(tid >> 1) * 32 + (tid & 1) * 16];
    *(s16x8*)d = u.v[0];
    *(s16x8*)(d + 8) = u.v[1];
  };
  auto compute = [&](int buf) {
    s16x8 af[4], bv[4];
    #pragma unroll
    for (int m = 0; m < 4; ++m)
      af[m] = *(const s16x8*)(&As[buf][(wr + m * 16 + lr) * 32 + lg * 8]);
    #pragma unroll
    for (int n = 0; n < 4; ++n)
      bv[n] = *(const s16x8*)(&Bs[buf][(wc + n * 16 + lr) * 32 + lg * 8]);
    #pragma unroll
    for (int m = 0; m < 4; ++m)
      #pragma unroll
      for (int n = 0; n < 4; ++n)
        acc[m][n] = __builtin_amdgcn_mfma_f32_16x16x32_bf16(af[m], bv[n],
                                                            acc[m][n], 0, 0, 0);
  };

  stageB(0, 0);
  loadA(0);
  writeA(0);
  __syncthreads();

  #pragma unroll 2
  for (int kt = 0; kt < 128; ++kt) {
    const int buf = kt & 1;
    if (kt + 1 < 128) {
      stageB(kt + 1, buf ^ 1);
      loadA(kt + 1);
    }
    compute(buf);
    if (kt + 1 < 128) writeA(buf ^ 1);
    __syncthreads();
  }

  const int orow0 = tm * 128 + wr + lg * 4;
  const int ocol0 = tn * 128 + wc + lr;
  float bvv[4];
  #pragma unroll
  for (int n = 0; n < 4; ++n) bvv[n] = bias[ocol0 + n * 16];
  #pragma unroll
  for (int m = 0; m < 4; ++m) {
    #pragma unroll
    for (int r = 0; r < 4; ++r) {
      float* op = out + (size_t)(orow0 + m * 16 + r) * N_DIM + ocol0;
      #pragma unroll
      for (int n = 0; n < 4; ++n)
        op[n * 16] = acc[m][n][r] + bvv[n];
    }
  }
}

extern "C" void kernel_launch(void* const* d_in, const int* in_sizes, int n_in,
                              void* d_out, int out_size, void* d_ws, size_t ws_size,
                              hipStream_t stream) {
  const float* x    = (const float*)d_in[0];
  const int*   qw   = (const int*)d_in[1];
  const float* s1   = (const float*)d_in[2];
  const float* s2   = (const float*)d_in[3];
  const float* bias = (const float*)d_in[4];
  float* out = (float*)d_out;

  const size_t BP_BYTES = (size_t)K_DIM * N_DIM * 2;    // 32 MiB
  const size_t XB_BYTES = (size_t)M_ROWS * K_DIM * 2;   // 64 MiB
  bf16* Bp = (bf16*)d_ws;

  if (ws_size >= BP_BYTES + XB_BYTES) {
    bf16* Ap = (bf16*)((char*)d_ws + BP_BYTES);
    dequant8_k<<<dim3(2048), dim3(256), 0, stream>>>(qw, s1, s2, Bp);
    xcast_k<<<dim3(16384), dim3(256), 0, stream>>>(x, Ap);
    gemm8_k<<<dim3(512), dim3(512), 0, stream>>>(Ap, Bp, bias, out);
  } else {
    dequant_f<<<dim3(8192), dim3(256), 0, stream>>>(qw, s1, s2, Bp);
    gemmf_k<<<dim3(2048), dim3(256), 0, stream>>>(x, Bp, bias, out);
  }
}

// Round 5
// 265.918 us; speedup vs baseline: 1.4461x; 1.0312x over previous
//
#include <hip/hip_runtime.h>
#include <hip/hip_bf16.h>
#include <stdint.h>

#define M_ROWS 8192
#define K_DIM  4096
#define N_DIM  4096

using bf16 = __hip_bfloat16;
typedef __attribute__((ext_vector_type(4))) float f32x4;
typedef __attribute__((ext_vector_type(8))) short s16x8;

__device__ __forceinline__ void gll16(const bf16* g, bf16* l) {
  __builtin_amdgcn_global_load_lds(
      (const __attribute__((address_space(1))) void*)g,
      (__attribute__((address_space(3))) void*)l, 16, 0, 0);
}

// ===========================================================================
// PATH A: panel layouts, LDS swizzle baked into global layout.
// A panels: chunk[(tm*64+kt)*2+kh] of 8192 bf16 = [row 256][slot 4][8],
//   data(row,slot_store) = x[tm*256+row][kt*64+kh*32+(slot_store^((row>>1)&3))*8..]
// B panels: chunk[(tn*64+kt)*2+kh] = [col 256][slot 4][8],
//   data(col,slot_store) = W[kt*64+kh*32+(slot_store^((col>>1)&3))*8+j][tn*256+col]
// Fused pre-pass: blocks [0,2048) dequant W -> Bp, blocks [2048,18432) cast
// x -> Ap. Bodies verbatim from the round-2-verified kernels.
// ===========================================================================
__global__ __launch_bounds__(256) void prep_k(
    const int* __restrict__ qw, const float* __restrict__ s1,
    const float* __restrict__ s2, const float* __restrict__ x,
    bf16* __restrict__ Bp, bf16* __restrict__ Ap)
{
  const int bid = blockIdx.x;
  if (bid < 2048) {
    // ---- dequant ----
    const int t = bid * 256 + threadIdx.x;   // 0..524287
    const int o = t & 4095;
    const int q = t >> 12;          // 0..127
    const int r0 = q << 2;
    const int g = r0 >> 4;
    const int nt = o >> 8, col = o & 255;
    const int kt = q >> 1, kh = q & 1;
    const int sw = (col >> 1) & 3;
    const float a = s1[g * 4096 + o] * 0.5f;   // codes >= 0 (q>=8)
    const float b = s2[g * 4096 + o] * 0.5f;   // codes <  0
    const uint64_t lo = 0x00FFFEFDFCFAF8F4ull;  // 2*CODE, q=0..7
    const uint64_t hi = 0x0C08060403020100ull;  // 2*CODE, q=8..15
    bf16* dst = Bp + (((size_t)((nt * 64 + kt) * 2 + kh)) << 13) + col * 32;
    #pragma unroll
    for (int j = 0; j < 4; ++j) {
      const uint32_t wbits = (uint32_t)qw[(size_t)(r0 + j) * 4096 + o];
      union { bf16 h[8]; s16x8 v; } u;
      #pragma unroll
      for (int i = 0; i < 8; ++i) {
        const int qc = (wbits >> (4 * i)) & 15;
        const uint64_t pk = (qc & 8) ? hi : lo;
        const int c2 = (int)(int8_t)(uint8_t)(pk >> ((qc & 7) * 8));
        const float sc = (qc & 8) ? a : b;
        u.h[i] = __float2bfloat16((float)c2 * sc);
      }
      *(s16x8*)(dst + ((j ^ sw) << 3)) = u.v;
    }
  } else {
    // ---- x cast ----
    const int t = (bid - 2048) * 256 + threadIdx.x;   // 0..4194303
    const int s_lin = t & 3;
    const int kh = (t >> 2) & 1;
    const int kt = (t >> 3) & 63;
    const int m  = t >> 9;
    const int tm = m >> 8, row = m & 255;
    const float* s = x + (size_t)m * 4096 + (kt * 64 + kh * 32 + s_lin * 8);
    f32x4 v0 = *(const f32x4*)s;
    f32x4 v1 = *(const f32x4*)(s + 4);
    union { bf16 h[8]; s16x8 v; } u;
    #pragma unroll
    for (int j = 0; j < 4; ++j) {
      u.h[j]     = __float2bfloat16(v0[j]);
      u.h[4 + j] = __float2bfloat16(v1[j]);
    }
    const int ss = s_lin ^ ((row >> 1) & 3);
    bf16* dst = Ap + (((size_t)((tm * 64 + kt) * 2 + kh)) << 13) + row * 32 + ss * 8;
    *(s16x8*)dst = u.v;
  }
}

// ---------------------------------------------------------------------------
// 8-phase 256x256 GEMM, BK=64, 8 waves (2Mx4N), 128 KiB LDS dbuf.
// Sync schedule = round-2-exact (deterministically verified): stage A0' at
// p0, B0' at p1, A1' at p2, B1' at p3; vmcnt(4) after p1 and p3 MFMAs.
// Ledger (gll units; entering each tile out = [A1(t),B1(t)] = 4):
//   p0 +A0' -> 6 ; p1 +B0' -> 8, VMW(4) clears A1(t),B1(t) ; p2 +A1' -> 6 ;
//   p3 +B1' -> 8, VMW(4) clears A0',B0'.
// Changes vs round 2 (both vmcnt-semantics-free):
//  - p0/p2 end-barriers REMOVED: consecutive phases read the same buf and
//    glls write only buf^1, so only p1/p3-end barriers (publishing after
//    VMW) and the pre-MFMA PH_SYNC barriers are correctness-critical.
//  - barriers/waits carry "memory" clobber + sched_barrier(0) (strictly
//    more compile-time ordering than round 2; no extra runtime ops).
// ---------------------------------------------------------------------------
#define BAR()                                                         \
    asm volatile("s_barrier" ::: "memory");                           \
    __builtin_amdgcn_sched_barrier(0)

#define PH_SYNC()                                                     \
    asm volatile("s_barrier" ::: "memory");                           \
    asm volatile("s_waitcnt lgkmcnt(0)" ::: "memory");                \
    __builtin_amdgcn_sched_barrier(0)

#define VMW(N)                                                        \
    asm volatile("s_waitcnt vmcnt(" #N ")" ::: "memory");             \
    __builtin_amdgcn_sched_barrier(0)

#define MFMA16(MH)                                                    \
    __builtin_amdgcn_s_setprio(1);                                    \
    _Pragma("unroll")                                                 \
    for (int m = 0; m < 4; ++m) {                                     \
      _Pragma("unroll")                                               \
      for (int n = 0; n < 4; ++n)                                     \
        acc[(MH)*4+m][n] = __builtin_amdgcn_mfma_f32_16x16x32_bf16(   \
            af[m], bb[n], acc[(MH)*4+m][n], 0, 0, 0);                 \
    }                                                                 \
    __builtin_amdgcn_s_setprio(0)

#define KTILE(BUF, NK2, PRE, VM)                                      \
  {                                                                   \
    const bf16* A0_ = &lds[BUF][0][0];                                \
    const bf16* A1_ = &lds[BUF][1][0];                                \
    const bf16* B0_ = &lds[BUF][2][0];                                \
    const bf16* B1_ = &lds[BUF][3][0];                                \
    /* p0: (mh0,kk0) */                                               \
    _Pragma("unroll")                                                 \
    for (int m = 0; m < 4; ++m) af[m] = *(const s16x8*)(A0_ + aoff + m * 512); \
    _Pragma("unroll")                                                 \
    for (int n = 0; n < 4; ++n) bb[n] = *(const s16x8*)(B0_ + boff + n * 512); \
    if (PRE) stage(Ab, (NK2), &lds[(BUF)^1][0][0]);                   \
    PH_SYNC();                                                        \
    MFMA16(0);                                                        \
    /* p1: (mh1,kk0) */                                               \
    _Pragma("unroll")                                                 \
    for (int m = 0; m < 4; ++m) af[m] = *(const s16x8*)(A0_ + aoff + (m + 4) * 512); \
    if (PRE) stage(Bb, (NK2), &lds[(BUF)^1][2][0]);                   \
    PH_SYNC();                                                        \
    MFMA16(1);                                                        \
    VMW(VM);                                                          \
    BAR();                                                            \
    /* p2: (mh0,kk1) */                                               \
    _Pragma("unroll")                                                 \
    for (int m = 0; m < 4; ++m) af[m] = *(const s16x8*)(A1_ + aoff + m * 512); \
    _Pragma("unroll")                                                 \
    for (int n = 0; n < 4; ++n) bb[n] = *(const s16x8*)(B1_ + boff + n * 512); \
    if (PRE) stage(Ab, (NK2) + 1, &lds[(BUF)^1][1][0]);               \
    PH_SYNC();                                                        \
    MFMA16(0);                                                        \
    /* p3: (mh1,kk1) */                                               \
    _Pragma("unroll")                                                 \
    for (int m = 0; m < 4; ++m) af[m] = *(const s16x8*)(A1_ + aoff + (m + 4) * 512); \
    if (PRE) stage(Bb, (NK2) + 1, &lds[(BUF)^1][3][0]);               \
    PH_SYNC();                                                        \
    MFMA16(1);                                                        \
    VMW(VM);                                                          \
    BAR();                                                            \
  }

__global__ __launch_bounds__(512, 2) void gemm8_k(
    const bf16* __restrict__ Ap, const bf16* __restrict__ Bp,
    const float* __restrict__ bias, float* __restrict__ out)
{
  __shared__ bf16 lds[2][4][8192];   // [buf][A-k0, A-k1, B-k0, B-k1]  128 KiB

  const int id  = blockIdx.x;
  const int swz = (id & 7) * 64 + (id >> 3);   // 512 % 8 == 0: bijective
  const int tm  = swz >> 4;      // 0..31
  const int tn  = swz & 15;      // 0..15
  const int tid = (int)threadIdx.x;
  const int lane = tid & 63;
  const int w   = tid >> 6;
  const int wr  = w >> 2;        // 0..1
  const int wc  = w & 3;         // 0..3
  const int lr  = lane & 15;
  const int lg  = lane >> 4;
  const int sl  = (lg ^ ((lr >> 1) & 3)) << 3;      // swizzled slot (elems)
  const int aoff = (wr * 128 + lr) * 32 + sl;
  const int boff = (wc * 64 + lr) * 32 + sl;

  const bf16* Ab = Ap + ((size_t)tm << 20);
  const bf16* Bb = Bp + ((size_t)tn << 20);

  f32x4 acc[8][4];
  #pragma unroll
  for (int m = 0; m < 8; ++m)
    #pragma unroll
    for (int n = 0; n < 4; ++n) acc[m][n] = (f32x4){0.f, 0.f, 0.f, 0.f};

  auto stage = [&](const bf16* base, int c, bf16* dst) {
    const bf16* s = base + ((size_t)c << 13) + tid * 8;
    gll16(s, dst + tid * 8);
    gll16(s + 4096, dst + tid * 8 + 4096);
  };

  s16x8 af[4], bb[4];

  // prologue: stage tile0 in need-order A0,B0,A1,B1; wait first pair only
  stage(Ab, 0, &lds[0][0][0]);
  stage(Bb, 0, &lds[0][2][0]);
  stage(Ab, 1, &lds[0][1][0]);
  stage(Bb, 1, &lds[0][3][0]);
  VMW(4);
  BAR();

  // t=0 uses buf0 and stages chunks 2,3 (tile1)
  KTILE(0, 2, 1, 4);
  #pragma unroll 1
  for (int kt2 = 0; kt2 < 31; ++kt2) {
    KTILE(1, (4 * kt2 + 4), 1, 4);   // t = 2*kt2+1, stages tile t+1
    KTILE(0, (4 * kt2 + 6), 1, 4);   // t = 2*kt2+2
  }
  KTILE(1, 0, 0, 0);                 // t=63, drain

  // epilogue: D row=(lane>>4)*4+reg, col=lane&15
  const int orow0 = tm * 256 + wr * 128 + lg * 4;
  const int ocol0 = tn * 256 + wc * 64 + lr;
  float bv[4];
  #pragma unroll
  for (int n = 0; n < 4; ++n) bv[n] = bias[ocol0 + n * 16];
  #pragma unroll
  for (int m = 0; m < 8; ++m) {
    #pragma unroll
    for (int r = 0; r < 4; ++r) {
      float* op = out + (size_t)(orow0 + m * 16 + r) * N_DIM + ocol0;
      #pragma unroll
      for (int n = 0; n < 4; ++n) op[n * 16] = acc[m][n][r] + bv[n];
    }
  }
}

// ===========================================================================
// PATH B fallback (round-1 verified): 128^2 tile, fp32 A reg-staged.
// ===========================================================================
__global__ __launch_bounds__(256) void dequant_f(
    const int* __restrict__ qw, const float* __restrict__ s1,
    const float* __restrict__ s2, bf16* __restrict__ Bp)
{
  const int t = blockIdx.x * 256 + threadIdx.x;
  const int o = t & 4095;
  const int r = t >> 12;
  const int g = r >> 4;
  const int kt = r >> 2;
  const int kk0 = (r & 3) * 8;
  const uint32_t wbits = (uint32_t)qw[(size_t)r * 4096 + o];
  const float a = s1[g * 4096 + o] * 0.5f;
  const float b = s2[g * 4096 + o] * 0.5f;
  const uint64_t lo = 0x00FFFEFDFCFAF8F4ull;
  const uint64_t hi = 0x0C08060403020100ull;
  union { bf16 h[8]; s16x8 v; } u;
  #pragma unroll
  for (int j = 0; j < 8; ++j) {
    const int q = (wbits >> (4 * j)) & 15;
    const uint64_t pk = (q & 8) ? hi : lo;
    const int c2 = (int)(int8_t)(uint8_t)(pk >> ((q & 7) * 8));
    const float s = (q & 8) ? a : b;
    u.h[j] = __float2bfloat16((float)c2 * s);
  }
  const int nt = o >> 7, col = o & 127;
  bf16* dst = Bp + (((size_t)(nt * 128 + kt) * 128 + col) * 32 + kk0);
  *(s16x8*)dst = u.v;
}

__global__ __launch_bounds__(256) void gemmf_k(
    const float* __restrict__ x, const bf16* __restrict__ Bp,
    const float* __restrict__ bias, float* __restrict__ out)
{
  __shared__ bf16 As[2][4096];
  __shared__ bf16 Bs[2][4096];

  const int id  = blockIdx.x;
  const int swz = (id & 7) * 256 + (id >> 3);
  const int tm  = swz >> 5;
  const int tn  = swz & 31;
  const int tid = threadIdx.x;
  const int lane = tid & 63;
  const int w   = tid >> 6;
  const int wr  = (w >> 1) * 64;
  const int wc  = (w & 1) * 64;
  const int lr  = lane & 15;
  const int lg  = lane >> 4;

  f32x4 acc[4][4];
  #pragma unroll
  for (int m = 0; m < 4; ++m)
    #pragma unroll
    for (int n = 0; n < 4; ++n) acc[m][n] = (f32x4){0.f, 0.f, 0.f, 0.f};

  const bf16* bsrc = Bp + ((size_t)tn << 19);
  const float* asrc_f = x + ((size_t)(tm * 128 + (tid >> 1)) << 12) + (tid & 1) * 16;
  float areg[16];

  auto stageB = [&](int kt, int buf) {
    const bf16* bs = bsrc + ((size_t)kt << 12);
    gll16(bs + tid * 8,        &Bs[buf][tid * 8]);
    gll16(bs + 2048 + tid * 8, &Bs[buf][2048 + tid * 8]);
  };
  auto loadA = [&](int kt) {
    const float* s = asrc_f + ((size_t)kt << 5);
    #pragma unroll
    for (int i = 0; i < 4; ++i)
      *(f32x4*)(areg + i * 4) = *(const f32x4*)(s + i * 4);
  };
  auto writeA = [&](int buf) {
    union { bf16 h[16]; s16x8 v[2]; } u;
    #pragma unroll
    for (int i = 0; i < 16; ++i) u.h[i] = __float2bfloat16(areg[i]);
    bf16* d = &As[buf][(tid >> 1) * 32 + (tid & 1) * 16];
    *(s16x8*)d = u.v[0];
    *(s16x8*)(d + 8) = u.v[1];
  };
  auto compute = [&](int buf) {
    s16x8 af[4], bv[4];
    #pragma unroll
    for (int m = 0; m < 4; ++m)
      af[m] = *(const s16x8*)(&As[buf][(wr + m * 16 + lr) * 32 + lg * 8]);
    #pragma unroll
    for (int n = 0; n < 4; ++n)
      bv[n] = *(const s16x8*)(&Bs[buf][(wc + n * 16 + lr) * 32 + lg * 8]);
    #pragma unroll
    for (int m = 0; m < 4; ++m)
      #pragma unroll
      for (int n = 0; n < 4; ++n)
        acc[m][n] = __builtin_amdgcn_mfma_f32_16x16x32_bf16(af[m], bv[n],
                                                            acc[m][n], 0, 0, 0);
  };

  stageB(0, 0);
  loadA(0);
  writeA(0);
  __syncthreads();

  #pragma unroll 2
  for (int kt = 0; kt < 128; ++kt) {
    const int buf = kt & 1;
    if (kt + 1 < 128) {
      stageB(kt + 1, buf ^ 1);
      loadA(kt + 1);
    }
    compute(buf);
    if (kt + 1 < 128) writeA(buf ^ 1);
    __syncthreads();
  }

  const int orow0 = tm * 128 + wr + lg * 4;
  const int ocol0 = tn * 128 + wc + lr;
  float bvv[4];
  #pragma unroll
  for (int n = 0; n < 4; ++n) bvv[n] = bias[ocol0 + n * 16];
  #pragma unroll
  for (int m = 0; m < 4; ++m) {
    #pragma unroll
    for (int r = 0; r < 4; ++r) {
      float* op = out + (size_t)(orow0 + m * 16 + r) * N_DIM + ocol0;
      #pragma unroll
      for (int n = 0; n < 4; ++n)
        op[n * 16] = acc[m][n][r] + bvv[n];
    }
  }
}

extern "C" void kernel_launch(void* const* d_in, const int* in_sizes, int n_in,
                              void* d_out, int out_size, void* d_ws, size_t ws_size,
                              hipStream_t stream) {
  const float* x    = (const float*)d_in[0];
  const int*   qw   = (const int*)d_in[1];
  const float* s1   = (const float*)d_in[2];
  const float* s2   = (const float*)d_in[3];
  const float* bias = (const float*)d_in[4];
  float* out = (float*)d_out;

  const size_t BP_BYTES = (size_t)K_DIM * N_DIM * 2;    // 32 MiB
  const size_t XB_BYTES = (size_t)M_ROWS * K_DIM * 2;   // 64 MiB
  bf16* Bp = (bf16*)d_ws;

  if (ws_size >= BP_BYTES + XB_BYTES) {
    bf16* Ap = (bf16*)((char*)d_ws + BP_BYTES);
    prep_k<<<dim3(18432), dim3(256), 0, stream>>>(qw, s1, s2, x, Bp, Ap);
    gemm8_k<<<dim3(512), dim3(512), 0, stream>>>(Ap, Bp, bias, out);
  } else {
    dequant_f<<<dim3(8192), dim3(256), 0, stream>>>(qw, s1, s2, Bp);
    gemmf_k<<<dim3(2048), dim3(256), 0, stream>>>(x, Bp, bias, out);
  }
}